// Round 12
// baseline (670.133 us; speedup 1.0000x reference)
//
#include <hip/hip_runtime.h>

#define H   128

typedef __attribute__((ext_vector_type(8))) short short8;
typedef __attribute__((ext_vector_type(4))) float f32x4;

__device__ __forceinline__ unsigned int bfr(float f) {
  unsigned int u = __float_as_uint(f);
  return (u + 0x7fffu + ((u >> 16) & 1u)) >> 16;
}
__device__ __forceinline__ float bf_lo(unsigned int d) {
  return __uint_as_float(d << 16);
}
__device__ __forceinline__ float bf_hi(unsigned int d) {
  return __uint_as_float(d & 0xffff0000u);
}

// ---- prep: degree count + node encoder + weight pack (independent work) ---
__global__ __launch_bounds__(256) void prep(const int* __restrict__ dst,
    int* __restrict__ cnt, int E, const float* __restrict__ x,
    const float* __restrict__ node_w, const float* __restrict__ node_b,
    unsigned int* __restrict__ h2, int N, const float* __restrict__ lin1_w,
    const float* __restrict__ lin2_w, unsigned short* __restrict__ wp) {
  int gtid = blockIdx.x * 256 + threadIdx.x;
  int GT = gridDim.x * 256;
  for (int e = gtid; e < E; e += GT) atomicAdd(&cnt[dst[e]], 1);
  // node encoder: wave per row
  int lane = threadIdx.x & 63;
  int wg = blockIdx.x * 4 + (threadIdx.x >> 6);
  int NW = gridDim.x * 4;
  int c = lane * 2;
  float b0 = node_b[c], b1 = node_b[c + 1];
  for (int row = wg; row < N; row += NW) {
    const float* xr = x + (size_t)row * 64;
    float a0 = b0, a1 = b1;
#pragma unroll 8
    for (int k = 0; k < 64; ++k) {
      float xk = xr[k];
      float2 wv = *(const float2*)&node_w[k * H + c];
      a0 = fmaf(xk, wv.x, a0);
      a1 = fmaf(xk, wv.y, a1);
    }
    h2[(size_t)row * 64 + lane] = bfr(a0) | (bfr(a1) << 16);
  }
  // weight pack: fp32 [128][128] -> bf16 MFMA-B fragments
  for (int idx = gtid; idx < 6 * 16384; idx += GT) {
    int j = idx & 7, ln = (idx >> 3) & 63, ct = (idx >> 9) & 7;
    int kt = (idx >> 12) & 3, mat = idx >> 14;
    int l = mat >> 1, which = mat & 1;
    const float* w = (which == 0 ? lin1_w : lin2_w) + (size_t)l * H * H;
    int k = kt * 32 + (ln >> 4) * 8 + j;
    int n = ct * 16 + (ln & 15);
    wp[idx] = (unsigned short)bfr(w[k * H + n]);
  }
}

// ---------------- scan pass 1 ----------------------------------------------
__global__ __launch_bounds__(256) void block_sum(const int* __restrict__ cnt,
    int* __restrict__ bsum, int N) {
  int t = threadIdx.x;
  int i = blockIdx.x * 256 + t;
  int v = (i < N) ? cnt[i] : 0;
#pragma unroll
  for (int o = 32; o > 0; o >>= 1) v += __shfl_down(v, o, 64);
  __shared__ int wt[4];
  if ((t & 63) == 0) wt[t >> 6] = v;
  __syncthreads();
  if (t == 0) bsum[blockIdx.x] = wt[0] + wt[1] + wt[2] + wt[3];
}

// ---------------- scan pass 2 ----------------------------------------------
__global__ __launch_bounds__(1024) void scan_bsum(const int* __restrict__ bsum,
    int* __restrict__ bbase, int nb) {
  __shared__ int s[1024];
  int t = threadIdx.x;
  int v = (t < nb) ? bsum[t] : 0;
  s[t] = v;
  __syncthreads();
  for (int o = 1; o < 1024; o <<= 1) {
    int u = (t >= o) ? s[t - o] : 0;
    __syncthreads();
    s[t] += u;
    __syncthreads();
  }
  if (t < nb) bbase[t] = s[t] - v;
}

// ---------------- scan pass 3 ----------------------------------------------
__global__ __launch_bounds__(256) void scan_pass(const int* __restrict__ cnt,
    const int* __restrict__ bbase, int* __restrict__ off,
    int* __restrict__ cursor, int N) {
  int t = threadIdx.x;
  int i = blockIdx.x * 256 + t;
  int v = (i < N) ? cnt[i] : 0;
  int lane = t & 63;
  int incl = v;
#pragma unroll
  for (int o = 1; o < 64; o <<= 1) {
    int u = __shfl_up(incl, o, 64);
    if (lane >= o) incl += u;
  }
  __shared__ int wtot[4];
  int w = t >> 6;
  if (lane == 63) wtot[w] = incl;
  __syncthreads();
  if (t == 0) {
    int run = 0;
#pragma unroll
    for (int k = 0; k < 4; ++k) { int tmp = wtot[k]; wtot[k] = run; run += tmp; }
  }
  __syncthreads();
  int excl = incl - v + wtot[w] + bbase[blockIdx.x];
  if (i < N) { off[i] = excl; cursor[i] = excl; }
  if (i == N - 1) off[N] = excl + v;
}

// ---------------- CSR build: scatter {edge, src} pairs ---------------------
__global__ __launch_bounds__(256) void scatter_csr(const int* __restrict__ src,
    const int* __restrict__ dst, int* __restrict__ cursor,
    int2* __restrict__ es, int E) {
  int e = blockIdx.x * 256 + threadIdx.x;
  if (e < E) {
    int pos = atomicAdd(&cursor[dst[e]], 1);
    es[pos] = make_int2(e, src[e]);
  }
}

// ---- CSR aggregation: zb[n] = bf16( h[n] + sum relu(h[src]+ea[e]@ew+eb) ) -
// Wave-per-node, 4-edge unroll: 4 outstanding h gathers, one s_load chain
// per edge ({e,src} int2). No LDS, no barriers.
__global__ __launch_bounds__(256) void aggr_csr(const float* __restrict__ ea,
    const float* __restrict__ ew, const float* __restrict__ eb,
    const int2* __restrict__ es, const int* __restrict__ off,
    const unsigned int* __restrict__ h2, unsigned int* __restrict__ zb,
    int N) {
  int wid = threadIdx.x >> 6, lane = threadIdx.x & 63;
  int n = blockIdx.x * 4 + wid;
  if (n >= N) return;
  int beg = off[n], end = off[n + 1];
  int c = lane * 2;
  float2 wc[16];
#pragma unroll
  for (int k = 0; k < 16; ++k) wc[k] = *(const float2*)&ew[k * H + c];
  float2 bias = *(const float2*)&eb[c];
  float ax = 0.f, ay = 0.f;
  int i = beg;
  for (; i + 4 <= end; i += 4) {
    int2 p0 = es[i], p1 = es[i + 1], p2 = es[i + 2], p3 = es[i + 3];
    int e0 = __builtin_amdgcn_readfirstlane(p0.x);
    int s0 = __builtin_amdgcn_readfirstlane(p0.y);
    int e1 = __builtin_amdgcn_readfirstlane(p1.x);
    int s1 = __builtin_amdgcn_readfirstlane(p1.y);
    int e2 = __builtin_amdgcn_readfirstlane(p2.x);
    int s2 = __builtin_amdgcn_readfirstlane(p2.y);
    int e3 = __builtin_amdgcn_readfirstlane(p3.x);
    int s3 = __builtin_amdgcn_readfirstlane(p3.y);
    unsigned int hv0 = h2[(size_t)s0 * 64 + lane];
    unsigned int hv1 = h2[(size_t)s1 * 64 + lane];
    unsigned int hv2 = h2[(size_t)s2 * 64 + lane];
    unsigned int hv3 = h2[(size_t)s3 * 64 + lane];
    const float* a0 = ea + (size_t)e0 * 16;
    const float* a1 = ea + (size_t)e1 * 16;
    const float* a2 = ea + (size_t)e2 * 16;
    const float* a3 = ea + (size_t)e3 * 16;
    float x0 = bias.x, y0 = bias.y, x1 = bias.x, y1 = bias.y;
    float x2 = bias.x, y2 = bias.y, x3 = bias.x, y3 = bias.y;
#pragma unroll
    for (int k = 0; k < 16; ++k) {
      float a0k = a0[k], a1k = a1[k], a2k = a2[k], a3k = a3[k];
      float2 w = wc[k];
      x0 = fmaf(a0k, w.x, x0); y0 = fmaf(a0k, w.y, y0);
      x1 = fmaf(a1k, w.x, x1); y1 = fmaf(a1k, w.y, y1);
      x2 = fmaf(a2k, w.x, x2); y2 = fmaf(a2k, w.y, y2);
      x3 = fmaf(a3k, w.x, x3); y3 = fmaf(a3k, w.y, y3);
    }
    ax += fmaxf(x0 + bf_lo(hv0), 0.f) + fmaxf(x1 + bf_lo(hv1), 0.f) +
          fmaxf(x2 + bf_lo(hv2), 0.f) + fmaxf(x3 + bf_lo(hv3), 0.f);
    ay += fmaxf(y0 + bf_hi(hv0), 0.f) + fmaxf(y1 + bf_hi(hv1), 0.f) +
          fmaxf(y2 + bf_hi(hv2), 0.f) + fmaxf(y3 + bf_hi(hv3), 0.f);
  }
  for (; i < end; ++i) {
    int2 p0 = es[i];
    int e0 = __builtin_amdgcn_readfirstlane(p0.x);
    int s0 = __builtin_amdgcn_readfirstlane(p0.y);
    unsigned int hv0 = h2[(size_t)s0 * 64 + lane];
    const float* a0 = ea + (size_t)e0 * 16;
    float x0 = bias.x, y0 = bias.y;
#pragma unroll
    for (int k = 0; k < 16; ++k) {
      float a0k = a0[k];
      x0 = fmaf(a0k, wc[k].x, x0);
      y0 = fmaf(a0k, wc[k].y, y0);
    }
    ax += fmaxf(x0 + bf_lo(hv0), 0.f);
    ay += fmaxf(y0 + bf_hi(hv0), 0.f);
  }
  unsigned int hn = h2[(size_t)n * 64 + lane];
  zb[(size_t)n * 64 + lane] =
      bfr(bf_lo(hn) + ax) | (bfr(bf_hi(hn) + ay) << 16);
}

// ---- MFMA GEMM1: t = zb @ w1 + b1 (fp32 out) + BN column sums -------------
__global__ __launch_bounds__(256) void mlp1m(const unsigned short* __restrict__ zb,
    const unsigned short* __restrict__ wp, const float* __restrict__ b1,
    float* __restrict__ tout, float* __restrict__ sum,
    float* __restrict__ sumsq, int N) {
  int tid = threadIdx.x;
  int wave = tid >> 6, lane = tid & 63;
  int q = lane >> 4, m = lane & 15;
  int r0 = blockIdx.x * 64 + wave * 16;
  f32x4 acc[8];
#pragma unroll
  for (int ct = 0; ct < 8; ++ct) acc[ct] = (f32x4){0.f, 0.f, 0.f, 0.f};
#pragma unroll
  for (int kt = 0; kt < 4; ++kt) {
    short8 a = *(const short8*)(zb + (size_t)(r0 + m) * H + kt * 32 + q * 8);
#pragma unroll
    for (int ct = 0; ct < 8; ++ct) {
      short8 b = *(const short8*)(wp + ((size_t)(kt * 8 + ct) * 64 + lane) * 8);
      acc[ct] = __builtin_amdgcn_mfma_f32_16x16x32_bf16(a, b, acc[ct], 0, 0, 0);
    }
  }
  __shared__ float red[2][H][16];
  int wq = wave * 4 + q;
#pragma unroll
  for (int ct = 0; ct < 8; ++ct) {
    int col = ct * 16 + m;
    float bias = b1[col];
    float s1 = 0.f, s2 = 0.f;
#pragma unroll
    for (int r = 0; r < 4; ++r) {
      int gr = r0 + q * 4 + r;
      float v = acc[ct][r] + bias;
      if (gr < N) {
        tout[(size_t)gr * H + col] = v;
        s1 += v;
        s2 += v * v;
      }
    }
    red[0][col][wq] = s1;
    red[1][col][wq] = s2;
  }
  __syncthreads();
  if (tid < H) {
    float a = 0.f, b = 0.f;
#pragma unroll
    for (int g = 0; g < 16; ++g) {
      a += red[0][tid][g];
      b += red[1][tid][g];
    }
    atomicAdd(&sum[tid], a);
    atomicAdd(&sumsq[tid], b);
  }
}

// ---- MFMA GEMM2 with fused BN-finalize prologue; bf16 h out or pool -------
__global__ __launch_bounds__(256) void mlp2m(const float* __restrict__ tin,
    const float* __restrict__ sums, const float* __restrict__ sumsqs,
    const float* __restrict__ bng, const float* __restrict__ bnb,
    const unsigned short* __restrict__ wp, const float* __restrict__ b2,
    unsigned short* __restrict__ hout, int N, float invN,
    const int* __restrict__ batch, float* __restrict__ pooled) {
  int tid = threadIdx.x;
  __shared__ float scs[H], shs[H];
  if (tid < H) {
    float mu = sums[tid] * invN;
    float var = sumsqs[tid] * invN - mu * mu;
    float inv = rsqrtf(var + 1e-5f);
    float sc = bng[tid] * inv;
    scs[tid] = sc;
    shs[tid] = bnb[tid] - mu * sc;
  }
  __syncthreads();
  int wave = tid >> 6, lane = tid & 63;
  int q = lane >> 4, m = lane & 15;
  int r0 = blockIdx.x * 64 + wave * 16;
  int row = r0 + m;
  f32x4 acc[8];
#pragma unroll
  for (int ct = 0; ct < 8; ++ct) acc[ct] = (f32x4){0.f, 0.f, 0.f, 0.f};
#pragma unroll
  for (int kt = 0; kt < 4; ++kt) {
    int c0 = kt * 32 + q * 8;
    f32x4 t0 = *(const f32x4*)(tin + (size_t)row * H + c0);
    f32x4 t1 = *(const f32x4*)(tin + (size_t)row * H + c0 + 4);
    short8 a;
#pragma unroll
    for (int j = 0; j < 4; ++j) {
      float v = fmaxf(fmaf(t0[j], scs[c0 + j], shs[c0 + j]), 0.f);
      a[j] = (short)bfr(v);
    }
#pragma unroll
    for (int j = 0; j < 4; ++j) {
      float v = fmaxf(fmaf(t1[j], scs[c0 + 4 + j], shs[c0 + 4 + j]), 0.f);
      a[4 + j] = (short)bfr(v);
    }
#pragma unroll
    for (int ct = 0; ct < 8; ++ct) {
      short8 b = *(const short8*)(wp + ((size_t)(kt * 8 + ct) * 64 + lane) * 8);
      acc[ct] = __builtin_amdgcn_mfma_f32_16x16x32_bf16(a, b, acc[ct], 0, 0, 0);
    }
  }
#pragma unroll
  for (int ct = 0; ct < 8; ++ct) {
    float bias = b2[ct * 16 + m];
#pragma unroll
    for (int r = 0; r < 4; ++r) acc[ct][r] = fmaxf(acc[ct][r] + bias, 0.f);
  }
  if (hout != nullptr) {
#pragma unroll
    for (int r = 0; r < 4; ++r) {
      int gr = r0 + q * 4 + r;
      if (gr < N) {
#pragma unroll
        for (int ct = 0; ct < 8; ++ct)
          hout[(size_t)gr * H + ct * 16 + m] = (unsigned short)bfr(acc[ct][r]);
      }
    }
  }
  if (pooled != nullptr) {
    int bprev = -1;
    float pa[8];
#pragma unroll
    for (int ct = 0; ct < 8; ++ct) pa[ct] = 0.f;
    for (int r = 0; r < 4; ++r) {
      int gr = r0 + q * 4 + r;
      if (gr >= N) break;
      int bb = batch[gr];
      if (bb != bprev && bprev >= 0) {
#pragma unroll
        for (int ct = 0; ct < 8; ++ct) {
          atomicAdd(&pooled[(size_t)bprev * H + ct * 16 + m], pa[ct]);
          pa[ct] = 0.f;
        }
      }
      bprev = bb;
#pragma unroll
      for (int ct = 0; ct < 8; ++ct) pa[ct] += acc[ct][r];
    }
    if (bprev >= 0) {
#pragma unroll
      for (int ct = 0; ct < 8; ++ct)
        atomicAdd(&pooled[(size_t)bprev * H + ct * 16 + m], pa[ct]);
    }
  }
}

// ---- final FC: out = pooled @ fc_w + fc_b ---------------------------------
__global__ __launch_bounds__(128) void fc_kernel(const float* __restrict__ pooled,
    const float* __restrict__ w, const float* __restrict__ b,
    float* __restrict__ out, int C) {
  int g = blockIdx.x;
  int j = threadIdx.x;
  __shared__ float p[H];
  p[j] = pooled[(size_t)g * H + j];
  __syncthreads();
  if (j < C) {
    float acc = b[j];
#pragma unroll 4
    for (int k = 0; k < H; ++k) acc = fmaf(p[k], w[k * C + j], acc);
    out[(size_t)g * C + j] = acc;
  }
}

extern "C" void kernel_launch(void* const* d_in, const int* in_sizes, int n_in,
                              void* d_out, int out_size, void* d_ws, size_t ws_size,
                              hipStream_t stream) {
  const float* x         = (const float*)d_in[0];
  const float* edge_attr = (const float*)d_in[1];
  const float* node_w    = (const float*)d_in[2];
  const float* node_b    = (const float*)d_in[3];
  const float* edge_w    = (const float*)d_in[4];
  const float* edge_b    = (const float*)d_in[5];
  const float* lin1_w    = (const float*)d_in[6];
  const float* lin1_b    = (const float*)d_in[7];
  const float* bn_g      = (const float*)d_in[8];
  const float* bn_b      = (const float*)d_in[9];
  const float* lin2_w    = (const float*)d_in[10];
  const float* lin2_b    = (const float*)d_in[11];
  const float* fc_w      = (const float*)d_in[12];
  const float* fc_b      = (const float*)d_in[13];
  const int*   edge_index= (const int*)d_in[14];
  const int*   batch     = (const int*)d_in[15];

  int N = in_sizes[0] / 64;       // 50000
  int E = in_sizes[1] / 16;       // 640000
  int C = in_sizes[13];           // 10
  int G = out_size / C;           // 512

  const int* src = edge_index;
  const int* dst = edge_index + E;

  int mblk = (N + 63) / 64;
  int Npad = mblk * 64;           // 50048
  int nb = (N + 255) / 256;       // 196

  float* t      = (float*)d_ws;              // [Npad,H] fp32
  // zero-region: pooled | sumsA | cnt  (one memset)
  float* pooled = t + (size_t)Npad * H;      // [G,H]
  float* sumsA  = pooled + (size_t)G * H;    // [3*256]
  int*   cnt    = (int*)(sumsA + 3 * 256);   // [N]
  size_t zbytes = ((size_t)G * H + 3 * 256 + N) * 4;
  int*   off    = cnt + N;                   // [N+2] (pad for alignment)
  int*   cursor = off + N + 2;               // [N]
  int2*  es     = (int2*)(cursor + N);       // [E] {edge, src}
  unsigned int* h2 = (unsigned int*)(es + E);        // [Npad,64] bf16x2
  unsigned int* zb = h2 + (size_t)Npad * 64;         // [Npad,64] bf16x2
  unsigned short* wp = (unsigned short*)(zb + (size_t)Npad * 64);  // 6*16384
  int* bsum  = (int*)(wp + 6 * 16384);       // [1024]
  int* bbase = bsum + 1024;                  // [1024]

  hipMemsetAsync(pooled, 0, zbytes, stream);
  prep<<<1024, 256, 0, stream>>>(dst, cnt, E, x, node_w, node_b, h2, N,
                                 lin1_w, lin2_w, wp);
  block_sum<<<nb, 256, 0, stream>>>(cnt, bsum, N);
  scan_bsum<<<1, 1024, 0, stream>>>(bsum, bbase, nb);
  scan_pass<<<nb, 256, 0, stream>>>(cnt, bbase, off, cursor, N);
  scatter_csr<<<(E + 255) / 256, 256, 0, stream>>>(src, dst, cursor, es, E);

  int ablk = (N + 3) / 4;
  for (int l = 0; l < 3; ++l) {
    aggr_csr<<<ablk, 256, 0, stream>>>(edge_attr, edge_w, edge_b, es, off,
                                       h2, zb, N);
    mlp1m<<<mblk, 256, 0, stream>>>((const unsigned short*)zb,
                                    wp + (size_t)(l * 2) * 16384,
                                    lin1_b + (size_t)l * H, t,
                                    sumsA + l * 256, sumsA + l * 256 + 128, N);
    bool last = (l == 2);
    mlp2m<<<mblk, 256, 0, stream>>>(t, sumsA + l * 256, sumsA + l * 256 + 128,
                                    bn_g + (size_t)l * H, bn_b + (size_t)l * H,
                                    wp + (size_t)(l * 2 + 1) * 16384,
                                    lin2_b + (size_t)l * H,
                                    last ? nullptr : (unsigned short*)h2, N,
                                    1.0f / N, batch, last ? pooled : nullptr);
  }

  fc_kernel<<<G, 128, 0, stream>>>(pooled, fc_w, fc_b, (float*)d_out, C);
}

// Round 13
// 605.160 us; speedup vs baseline: 1.1074x; 1.1074x over previous
//
#include <hip/hip_runtime.h>

#define H   128

typedef __attribute__((ext_vector_type(8))) short short8;
typedef __attribute__((ext_vector_type(4))) float f32x4;

__device__ __forceinline__ unsigned int bfr(float f) {
  unsigned int u = __float_as_uint(f);
  return (u + 0x7fffu + ((u >> 16) & 1u)) >> 16;
}
__device__ __forceinline__ float bf_lo(unsigned int d) {
  return __uint_as_float(d << 16);
}
__device__ __forceinline__ float bf_hi(unsigned int d) {
  return __uint_as_float(d & 0xffff0000u);
}

// ---------------- node encoder: h2 = bf16(x @ node_w + node_b) -------------
// Proven R6-R9 form: block per row, x staged via LDS (coalesced).
__global__ __launch_bounds__(128) void node_enc(const float* __restrict__ x,
    const float* __restrict__ w, const float* __restrict__ b,
    unsigned int* __restrict__ h2, int N) {
  int row = blockIdx.x;
  if (row >= N) return;
  int j = threadIdx.x;
  __shared__ float xs[64];
  if (j < 64) xs[j] = x[(size_t)row * 64 + j];
  __syncthreads();
  float acc = b[j];
#pragma unroll
  for (int k = 0; k < 64; ++k) acc = fmaf(xs[k], w[k * H + j], acc);
  float part = __shfl_down(acc, 1, 64);
  if ((j & 1) == 0) {
    unsigned int d = bfr(acc) | (bfr(part) << 16);
    h2[(size_t)row * 64 + (j >> 1)] = d;
  }
}

// ---------------- CSR build: degree count ----------------------------------
__global__ __launch_bounds__(256) void count_deg(const int* __restrict__ dst,
    int* __restrict__ cnt, int E) {
  int e = blockIdx.x * 256 + threadIdx.x;
  if (e < E) atomicAdd(&cnt[dst[e]], 1);
}

// ---------------- weight pack: fp32 [128][128] -> bf16 MFMA-B fragments ----
__global__ __launch_bounds__(256) void wpack(const float* __restrict__ w1,
    const float* __restrict__ w2, unsigned short* __restrict__ wp) {
  int idx = blockIdx.x * 256 + threadIdx.x;
  if (idx >= 6 * 16384) return;
  int j = idx & 7, ln = (idx >> 3) & 63, ct = (idx >> 9) & 7;
  int kt = (idx >> 12) & 3, mat = idx >> 14;
  int l = mat >> 1, which = mat & 1;
  const float* w = (which == 0 ? w1 : w2) + (size_t)l * H * H;
  int k = kt * 32 + (ln >> 4) * 8 + j;
  int n = ct * 16 + (ln & 15);
  wp[idx] = (unsigned short)bfr(w[k * H + n]);
}

// ---------------- scan pass 1 ----------------------------------------------
__global__ __launch_bounds__(256) void block_sum(const int* __restrict__ cnt,
    int* __restrict__ bsum, int N) {
  int t = threadIdx.x;
  int i = blockIdx.x * 256 + t;
  int v = (i < N) ? cnt[i] : 0;
#pragma unroll
  for (int o = 32; o > 0; o >>= 1) v += __shfl_down(v, o, 64);
  __shared__ int wt[4];
  if ((t & 63) == 0) wt[t >> 6] = v;
  __syncthreads();
  if (t == 0) bsum[blockIdx.x] = wt[0] + wt[1] + wt[2] + wt[3];
}

// ---------------- scan pass 2 ----------------------------------------------
__global__ __launch_bounds__(1024) void scan_bsum(const int* __restrict__ bsum,
    int* __restrict__ bbase, int nb) {
  __shared__ int s[1024];
  int t = threadIdx.x;
  int v = (t < nb) ? bsum[t] : 0;
  s[t] = v;
  __syncthreads();
  for (int o = 1; o < 1024; o <<= 1) {
    int u = (t >= o) ? s[t - o] : 0;
    __syncthreads();
    s[t] += u;
    __syncthreads();
  }
  if (t < nb) bbase[t] = s[t] - v;
}

// ---------------- scan pass 3 ----------------------------------------------
__global__ __launch_bounds__(256) void scan_pass(const int* __restrict__ cnt,
    const int* __restrict__ bbase, int* __restrict__ off,
    int* __restrict__ cursor, int N) {
  int t = threadIdx.x;
  int i = blockIdx.x * 256 + t;
  int v = (i < N) ? cnt[i] : 0;
  int lane = t & 63;
  int incl = v;
#pragma unroll
  for (int o = 1; o < 64; o <<= 1) {
    int u = __shfl_up(incl, o, 64);
    if (lane >= o) incl += u;
  }
  __shared__ int wtot[4];
  int w = t >> 6;
  if (lane == 63) wtot[w] = incl;
  __syncthreads();
  if (t == 0) {
    int run = 0;
#pragma unroll
    for (int k = 0; k < 4; ++k) { int tmp = wtot[k]; wtot[k] = run; run += tmp; }
  }
  __syncthreads();
  int excl = incl - v + wtot[w] + bbase[blockIdx.x];
  if (i < N) { off[i] = excl; cursor[i] = excl; }
  if (i == N - 1) off[N] = excl + v;
}

// ---------------- CSR build: scatter {edge, src} pairs ---------------------
__global__ __launch_bounds__(256) void scatter_csr(const int* __restrict__ src,
    const int* __restrict__ dst, int* __restrict__ cursor,
    int2* __restrict__ es, int E) {
  int e = blockIdx.x * 256 + threadIdx.x;
  if (e < E) {
    int pos = atomicAdd(&cursor[dst[e]], 1);
    es[pos] = make_int2(e, src[e]);
  }
}

// ---- CSR aggregation: zb[n] = bf16( h[n] + sum relu(h[src]+ea[e]@ew+eb) ) -
__global__ __launch_bounds__(256) void aggr_csr(const float* __restrict__ ea,
    const float* __restrict__ ew, const float* __restrict__ eb,
    const int2* __restrict__ es, const int* __restrict__ off,
    const unsigned int* __restrict__ h2, unsigned int* __restrict__ zb,
    int N) {
  int wid = threadIdx.x >> 6, lane = threadIdx.x & 63;
  int n = blockIdx.x * 4 + wid;
  if (n >= N) return;
  int beg = off[n], end = off[n + 1];
  int c = lane * 2;
  float2 wc[16];
#pragma unroll
  for (int k = 0; k < 16; ++k) wc[k] = *(const float2*)&ew[k * H + c];
  float2 bias = *(const float2*)&eb[c];
  float ax = 0.f, ay = 0.f;
  int i = beg;
  for (; i + 4 <= end; i += 4) {
    int2 p0 = es[i], p1 = es[i + 1], p2 = es[i + 2], p3 = es[i + 3];
    int e0 = __builtin_amdgcn_readfirstlane(p0.x);
    int s0 = __builtin_amdgcn_readfirstlane(p0.y);
    int e1 = __builtin_amdgcn_readfirstlane(p1.x);
    int s1 = __builtin_amdgcn_readfirstlane(p1.y);
    int e2 = __builtin_amdgcn_readfirstlane(p2.x);
    int s2 = __builtin_amdgcn_readfirstlane(p2.y);
    int e3 = __builtin_amdgcn_readfirstlane(p3.x);
    int s3 = __builtin_amdgcn_readfirstlane(p3.y);
    unsigned int hv0 = h2[(size_t)s0 * 64 + lane];
    unsigned int hv1 = h2[(size_t)s1 * 64 + lane];
    unsigned int hv2 = h2[(size_t)s2 * 64 + lane];
    unsigned int hv3 = h2[(size_t)s3 * 64 + lane];
    const float* a0 = ea + (size_t)e0 * 16;
    const float* a1 = ea + (size_t)e1 * 16;
    const float* a2 = ea + (size_t)e2 * 16;
    const float* a3 = ea + (size_t)e3 * 16;
    float x0 = bias.x, y0 = bias.y, x1 = bias.x, y1 = bias.y;
    float x2 = bias.x, y2 = bias.y, x3 = bias.x, y3 = bias.y;
#pragma unroll
    for (int k = 0; k < 16; ++k) {
      float a0k = a0[k], a1k = a1[k], a2k = a2[k], a3k = a3[k];
      float2 w = wc[k];
      x0 = fmaf(a0k, w.x, x0); y0 = fmaf(a0k, w.y, y0);
      x1 = fmaf(a1k, w.x, x1); y1 = fmaf(a1k, w.y, y1);
      x2 = fmaf(a2k, w.x, x2); y2 = fmaf(a2k, w.y, y2);
      x3 = fmaf(a3k, w.x, x3); y3 = fmaf(a3k, w.y, y3);
    }
    ax += fmaxf(x0 + bf_lo(hv0), 0.f) + fmaxf(x1 + bf_lo(hv1), 0.f) +
          fmaxf(x2 + bf_lo(hv2), 0.f) + fmaxf(x3 + bf_lo(hv3), 0.f);
    ay += fmaxf(y0 + bf_hi(hv0), 0.f) + fmaxf(y1 + bf_hi(hv1), 0.f) +
          fmaxf(y2 + bf_hi(hv2), 0.f) + fmaxf(y3 + bf_hi(hv3), 0.f);
  }
  for (; i < end; ++i) {
    int2 p0 = es[i];
    int e0 = __builtin_amdgcn_readfirstlane(p0.x);
    int s0 = __builtin_amdgcn_readfirstlane(p0.y);
    unsigned int hv0 = h2[(size_t)s0 * 64 + lane];
    const float* a0 = ea + (size_t)e0 * 16;
    float x0 = bias.x, y0 = bias.y;
#pragma unroll
    for (int k = 0; k < 16; ++k) {
      float a0k = a0[k];
      x0 = fmaf(a0k, wc[k].x, x0);
      y0 = fmaf(a0k, wc[k].y, y0);
    }
    ax += fmaxf(x0 + bf_lo(hv0), 0.f);
    ay += fmaxf(y0 + bf_hi(hv0), 0.f);
  }
  unsigned int hn = h2[(size_t)n * 64 + lane];
  zb[(size_t)n * 64 + lane] =
      bfr(bf_lo(hn) + ax) | (bfr(bf_hi(hn) + ay) << 16);
}

// ---- MFMA GEMM1: t = zb @ w1 + b1 (bf16 out) + BN column sums (fp32) ------
__global__ __launch_bounds__(256) void mlp1m(const unsigned short* __restrict__ zb,
    const unsigned short* __restrict__ wp, const float* __restrict__ b1,
    unsigned short* __restrict__ tout, float* __restrict__ sum,
    float* __restrict__ sumsq, int N) {
  int tid = threadIdx.x;
  int wave = tid >> 6, lane = tid & 63;
  int q = lane >> 4, m = lane & 15;
  int r0 = blockIdx.x * 64 + wave * 16;
  f32x4 acc[8];
#pragma unroll
  for (int ct = 0; ct < 8; ++ct) acc[ct] = (f32x4){0.f, 0.f, 0.f, 0.f};
#pragma unroll
  for (int kt = 0; kt < 4; ++kt) {
    short8 a = *(const short8*)(zb + (size_t)(r0 + m) * H + kt * 32 + q * 8);
#pragma unroll
    for (int ct = 0; ct < 8; ++ct) {
      short8 b = *(const short8*)(wp + ((size_t)(kt * 8 + ct) * 64 + lane) * 8);
      acc[ct] = __builtin_amdgcn_mfma_f32_16x16x32_bf16(a, b, acc[ct], 0, 0, 0);
    }
  }
  __shared__ float red[2][H][16];
  int wq = wave * 4 + q;
#pragma unroll
  for (int ct = 0; ct < 8; ++ct) {
    int col = ct * 16 + m;
    float bias = b1[col];
    float s1 = 0.f, s2 = 0.f;
#pragma unroll
    for (int r = 0; r < 4; ++r) {
      int gr = r0 + q * 4 + r;
      float v = acc[ct][r] + bias;
      if (gr < N) {
        tout[(size_t)gr * H + col] = (unsigned short)bfr(v);
        s1 += v;
        s2 += v * v;
      }
    }
    red[0][col][wq] = s1;
    red[1][col][wq] = s2;
  }
  __syncthreads();
  if (tid < H) {
    float a = 0.f, b = 0.f;
#pragma unroll
    for (int g = 0; g < 16; ++g) {
      a += red[0][tid][g];
      b += red[1][tid][g];
    }
    atomicAdd(&sum[tid], a);
    atomicAdd(&sumsq[tid], b);
  }
}

// ---- MFMA GEMM2 with fused BN-finalize prologue; bf16 h out or pool -------
__global__ __launch_bounds__(256) void mlp2m(const unsigned short* __restrict__ tin,
    const float* __restrict__ sums, const float* __restrict__ sumsqs,
    const float* __restrict__ bng, const float* __restrict__ bnb,
    const unsigned short* __restrict__ wp, const float* __restrict__ b2,
    unsigned short* __restrict__ hout, int N, float invN,
    const int* __restrict__ batch, float* __restrict__ pooled) {
  int tid = threadIdx.x;
  __shared__ float scs[H], shs[H];
  if (tid < H) {
    float mu = sums[tid] * invN;
    float var = sumsqs[tid] * invN - mu * mu;
    float inv = rsqrtf(var + 1e-5f);
    float sc = bng[tid] * inv;
    scs[tid] = sc;
    shs[tid] = bnb[tid] - mu * sc;
  }
  __syncthreads();
  int wave = tid >> 6, lane = tid & 63;
  int q = lane >> 4, m = lane & 15;
  int r0 = blockIdx.x * 64 + wave * 16;
  int row = r0 + m;
  f32x4 acc[8];
#pragma unroll
  for (int ct = 0; ct < 8; ++ct) acc[ct] = (f32x4){0.f, 0.f, 0.f, 0.f};
#pragma unroll
  for (int kt = 0; kt < 4; ++kt) {
    int c0 = kt * 32 + q * 8;
    uint4 tv = *(const uint4*)(tin + (size_t)row * H + c0);
    short8 a;
    float v;
    v = fmaxf(fmaf(bf_lo(tv.x), scs[c0 + 0], shs[c0 + 0]), 0.f); a[0] = (short)bfr(v);
    v = fmaxf(fmaf(bf_hi(tv.x), scs[c0 + 1], shs[c0 + 1]), 0.f); a[1] = (short)bfr(v);
    v = fmaxf(fmaf(bf_lo(tv.y), scs[c0 + 2], shs[c0 + 2]), 0.f); a[2] = (short)bfr(v);
    v = fmaxf(fmaf(bf_hi(tv.y), scs[c0 + 3], shs[c0 + 3]), 0.f); a[3] = (short)bfr(v);
    v = fmaxf(fmaf(bf_lo(tv.z), scs[c0 + 4], shs[c0 + 4]), 0.f); a[4] = (short)bfr(v);
    v = fmaxf(fmaf(bf_hi(tv.z), scs[c0 + 5], shs[c0 + 5]), 0.f); a[5] = (short)bfr(v);
    v = fmaxf(fmaf(bf_lo(tv.w), scs[c0 + 6], shs[c0 + 6]), 0.f); a[6] = (short)bfr(v);
    v = fmaxf(fmaf(bf_hi(tv.w), scs[c0 + 7], shs[c0 + 7]), 0.f); a[7] = (short)bfr(v);
#pragma unroll
    for (int ct = 0; ct < 8; ++ct) {
      short8 b = *(const short8*)(wp + ((size_t)(kt * 8 + ct) * 64 + lane) * 8);
      acc[ct] = __builtin_amdgcn_mfma_f32_16x16x32_bf16(a, b, acc[ct], 0, 0, 0);
    }
  }
#pragma unroll
  for (int ct = 0; ct < 8; ++ct) {
    float bias = b2[ct * 16 + m];
#pragma unroll
    for (int r = 0; r < 4; ++r) acc[ct][r] = fmaxf(acc[ct][r] + bias, 0.f);
  }
  if (hout != nullptr) {
#pragma unroll
    for (int r = 0; r < 4; ++r) {
      int gr = r0 + q * 4 + r;
      if (gr < N) {
#pragma unroll
        for (int ct = 0; ct < 8; ++ct)
          hout[(size_t)gr * H + ct * 16 + m] = (unsigned short)bfr(acc[ct][r]);
      }
    }
  }
  if (pooled != nullptr) {
    int bprev = -1;
    float pa[8];
#pragma unroll
    for (int ct = 0; ct < 8; ++ct) pa[ct] = 0.f;
    for (int r = 0; r < 4; ++r) {
      int gr = r0 + q * 4 + r;
      if (gr >= N) break;
      int bb = batch[gr];
      if (bb != bprev && bprev >= 0) {
#pragma unroll
        for (int ct = 0; ct < 8; ++ct) {
          atomicAdd(&pooled[(size_t)bprev * H + ct * 16 + m], pa[ct]);
          pa[ct] = 0.f;
        }
      }
      bprev = bb;
#pragma unroll
      for (int ct = 0; ct < 8; ++ct) pa[ct] += acc[ct][r];
    }
    if (bprev >= 0) {
#pragma unroll
      for (int ct = 0; ct < 8; ++ct)
        atomicAdd(&pooled[(size_t)bprev * H + ct * 16 + m], pa[ct]);
    }
  }
}

// ---- final FC: out = pooled @ fc_w + fc_b ---------------------------------
__global__ __launch_bounds__(128) void fc_kernel(const float* __restrict__ pooled,
    const float* __restrict__ w, const float* __restrict__ b,
    float* __restrict__ out, int C) {
  int g = blockIdx.x;
  int j = threadIdx.x;
  __shared__ float p[H];
  p[j] = pooled[(size_t)g * H + j];
  __syncthreads();
  if (j < C) {
    float acc = b[j];
#pragma unroll 4
    for (int k = 0; k < H; ++k) acc = fmaf(p[k], w[k * C + j], acc);
    out[(size_t)g * C + j] = acc;
  }
}

extern "C" void kernel_launch(void* const* d_in, const int* in_sizes, int n_in,
                              void* d_out, int out_size, void* d_ws, size_t ws_size,
                              hipStream_t stream) {
  const float* x         = (const float*)d_in[0];
  const float* edge_attr = (const float*)d_in[1];
  const float* node_w    = (const float*)d_in[2];
  const float* node_b    = (const float*)d_in[3];
  const float* edge_w    = (const float*)d_in[4];
  const float* edge_b    = (const float*)d_in[5];
  const float* lin1_w    = (const float*)d_in[6];
  const float* lin1_b    = (const float*)d_in[7];
  const float* bn_g      = (const float*)d_in[8];
  const float* bn_b      = (const float*)d_in[9];
  const float* lin2_w    = (const float*)d_in[10];
  const float* lin2_b    = (const float*)d_in[11];
  const float* fc_w      = (const float*)d_in[12];
  const float* fc_b      = (const float*)d_in[13];
  const int*   edge_index= (const int*)d_in[14];
  const int*   batch     = (const int*)d_in[15];

  int N = in_sizes[0] / 64;       // 50000
  int E = in_sizes[1] / 16;       // 640000
  int C = in_sizes[13];           // 10
  int G = out_size / C;           // 512

  const int* src = edge_index;
  const int* dst = edge_index + E;

  int mblk = (N + 63) / 64;
  int Npad = mblk * 64;           // 50048
  int nb = (N + 255) / 256;       // 196

  unsigned short* t = (unsigned short*)d_ws;   // [Npad,H] bf16
  // zero-region: pooled | sumsA | cnt  (one memset)
  float* pooled = (float*)(t + (size_t)Npad * H);  // [G,H]
  float* sumsA  = pooled + (size_t)G * H;          // [3*256]
  int*   cnt    = (int*)(sumsA + 3 * 256);         // [N]
  size_t zbytes = ((size_t)G * H + 3 * 256 + N) * 4;
  int*   off    = cnt + N;                         // [N+2]
  int*   cursor = off + N + 2;                     // [N]
  int2*  es     = (int2*)(cursor + N);             // [E]
  unsigned int* h2 = (unsigned int*)(es + E);          // [Npad,64] bf16x2
  unsigned int* zb = h2 + (size_t)Npad * 64;           // [Npad,64] bf16x2
  unsigned short* wp = (unsigned short*)(zb + (size_t)Npad * 64);  // 6*16384
  int* bsum  = (int*)(wp + 6 * 16384);             // [1024]
  int* bbase = bsum + 1024;                        // [1024]

  hipMemsetAsync(pooled, 0, zbytes, stream);
  count_deg<<<(E + 255) / 256, 256, 0, stream>>>(dst, cnt, E);
  node_enc<<<N, 128, 0, stream>>>(x, node_w, node_b, h2, N);
  wpack<<<(6 * 16384 + 255) / 256, 256, 0, stream>>>(lin1_w, lin2_w, wp);
  block_sum<<<nb, 256, 0, stream>>>(cnt, bsum, N);
  scan_bsum<<<1, 1024, 0, stream>>>(bsum, bbase, nb);
  scan_pass<<<nb, 256, 0, stream>>>(cnt, bbase, off, cursor, N);
  scatter_csr<<<(E + 255) / 256, 256, 0, stream>>>(src, dst, cursor, es, E);

  int ablk = (N + 3) / 4;
  for (int l = 0; l < 3; ++l) {
    aggr_csr<<<ablk, 256, 0, stream>>>(edge_attr, edge_w, edge_b, es, off,
                                       h2, zb, N);
    mlp1m<<<mblk, 256, 0, stream>>>((const unsigned short*)zb,
                                    wp + (size_t)(l * 2) * 16384,
                                    lin1_b + (size_t)l * H, t,
                                    sumsA + l * 256, sumsA + l * 256 + 128, N);
    bool last = (l == 2);
    mlp2m<<<mblk, 256, 0, stream>>>(t, sumsA + l * 256, sumsA + l * 256 + 128,
                                    bn_g + (size_t)l * H, bn_b + (size_t)l * H,
                                    wp + (size_t)(l * 2 + 1) * 16384,
                                    lin2_b + (size_t)l * H,
                                    last ? nullptr : (unsigned short*)h2, N,
                                    1.0f / N, batch, last ? pooled : nullptr);
  }

  fc_kernel<<<G, 128, 0, stream>>>(pooled, fc_w, fc_b, (float*)d_out, C);
}